// Round 3
// baseline (327.928 us; speedup 1.0000x reference)
//
#include <hip/hip_runtime.h>
#include <hip/hip_bf16.h>
#include <cstdint>
#include <cstddef>

#define BB 128
#define SS 4096
#define HH 128
#define N1 256
#define N2 64
#define TROWS 64            // rows per tile
#define TILES 4             // tiles per block
#define BROWS (TROWS*TILES) // 256 rows per block (256 | 4096 -> one b per block)

typedef __bf16 bf16x8 __attribute__((ext_vector_type(8)));
typedef __bf16 bf16x4 __attribute__((ext_vector_type(4)));
typedef float  f32x4  __attribute__((ext_vector_type(4)));

// ---------------------------------------------------------------------------
// Prologue.
// w1f: A-frags of W1^T (== B-frags of W1). frag(g 0..15, ks 0..7):
//   val[l][j] = W1[32ks + 8*(l>>4) + j][16g + (l&15)]
// w2f: A-frags of W2^T with the k-slot relabel that matches layer-1's C/D
//   ownership. frag(mt2 0..3, ks' 0..7):
//   val[l][j] = W2[c][16*mt2 + (l&15)],  c = 16*(ks' + 8*(j>>2)) + 4*(l>>4) + (j&3)
// Relabel derivation: h1 col c (g=c>>4, q=(c>>2)&3, reg=c&3) lives in D-frag
// (mt=g&3 of wave g>>2) reg 'reg' of lane-group q -> assigned k-slot
// 32*(g&7) + 8q + 4*(g>>3) + reg. Bijective; j=0..3 <-> mt-half g>>3=0,
// j=4..7 <-> g>>3=1.
// ---------------------------------------------------------------------------
__global__ __launch_bounds__(256) void conv_weights(
    const float* __restrict__ W1, const float* __restrict__ W2,
    __bf16* __restrict__ w1f, __bf16* __restrict__ w2f)
{
    int tid = blockIdx.x * 256 + threadIdx.x;
    if (tid < 8192) {
        int lane = tid & 63, ks = (tid >> 6) & 7, g = tid >> 9;
        int col = 16 * g + (lane & 15);
        int kbase = 32 * ks + 8 * (lane >> 4);
        bf16x8 v;
#pragma unroll
        for (int j = 0; j < 8; ++j) v[j] = (__bf16)W1[(size_t)(kbase + j) * N1 + col];
        *(bf16x8*)(w1f + (size_t)tid * 8) = v;
    } else if (tid < 10240) {
        int s = tid - 8192;
        int lane = s & 63, ksp = (s >> 6) & 7, mt2 = s >> 9;
        int q = lane >> 4, ln = lane & 15;
        bf16x8 v;
#pragma unroll
        for (int j = 0; j < 8; ++j) {
            int c = 16 * (ksp + 8 * (j >> 2)) + 4 * q + (j & 3);
            v[j] = (__bf16)W2[(size_t)c * N2 + 16 * mt2 + ln];
        }
        *(bf16x8*)(w2f + (size_t)s * 8) = v;
    }
}

// ---------------------------------------------------------------------------
// Main kernel. 4 waves; wave w owns h1 cols 64w..64w+63 in L1 (m-split) and
// rows 16w..16w+15 in L2 (n-split). Per block: 4 tiles of 64 rows,
// double-buffered X staging (reg prefetch during L1 MFMAs).
// newn's K-half of layer 1 is row- and tile-independent -> folded into accn
// once per block (saves 40% of L1 MFMAs).
// h1 handoff: packed ds_write_b64 by k-slot (relabel above) into
// h1f[row][kslot] with 16B-unit XOR swizzle (u ^= row&7); L2 B-frags are one
// ds_read_b128 each.
// ---------------------------------------------------------------------------
__global__ __launch_bounds__(256, 2) void edge_mlp_mfma2(
    const float* __restrict__ nodes, const float* __restrict__ newn,
    const float* __restrict__ b1, const float* __restrict__ b2,
    const float* __restrict__ W3, const float* __restrict__ b3,
    const __bf16* __restrict__ w1f, const __bf16* __restrict__ w2f,
    float* __restrict__ out)
{
    __shared__ uint4 xf[2][1024];   // X frags (nodes K-half), 16 KB per buffer
    __shared__ uint4 h1f[2048];     // h1 by [row][kslot-unit], 32 KB

    const int t = threadIdx.x;
    const int w = t >> 6, l = t & 63, q = l >> 4, ln = l & 15;
    const size_t row0 = (size_t)blockIdx.x * BROWS;
    const int b = (int)(row0 >> 12);

    // ---- per-block: newn B-frags (K-slots 128..255) ----
    bf16x8 nfrag[4];
#pragma unroll
    for (int k4 = 0; k4 < 4; ++k4) {
        const float* np = newn + b * HH + 32 * k4 + 8 * q;
        float4 f0 = *(const float4*)np, f1 = *(const float4*)(np + 4);
        nfrag[k4][0] = (__bf16)f0.x; nfrag[k4][1] = (__bf16)f0.y;
        nfrag[k4][2] = (__bf16)f0.z; nfrag[k4][3] = (__bf16)f0.w;
        nfrag[k4][4] = (__bf16)f1.x; nfrag[k4][5] = (__bf16)f1.y;
        nfrag[k4][6] = (__bf16)f1.z; nfrag[k4][7] = (__bf16)f1.w;
    }

    // ---- per-block: accn[mt] = b1 + W1^T(newn half) . newn (row-independent)
    f32x4 accn[4];
#pragma unroll
    for (int mt = 0; mt < 4; ++mt) {
        float4 bv = *(const float4*)(b1 + 16 * (4 * w + mt) + 4 * q);
        accn[mt][0] = bv.x; accn[mt][1] = bv.y; accn[mt][2] = bv.z; accn[mt][3] = bv.w;
    }
#pragma unroll
    for (int k4 = 0; k4 < 4; ++k4)
#pragma unroll
        for (int mt = 0; mt < 4; ++mt) {
            bf16x8 a = *(const bf16x8*)(w1f + ((size_t)((4 * w + mt) * 8 + 4 + k4) * 64 + l) * 8);
            accn[mt] = __builtin_amdgcn_mfma_f32_16x16x32_bf16(a, nfrag[k4], accn[mt], 0, 0, 0);
        }

    // ---- stage X_0 ----
    float4 pf[8];
    {
        const float* srcb = nodes + row0 * HH;
#pragma unroll
        for (int i = 0; i < 4; ++i) {
            int idx = i * 256 + t;
            const float* s = srcb + (size_t)(idx >> 4) * HH + 8 * (idx & 15);
            pf[2 * i]     = *(const float4*)s;
            pf[2 * i + 1] = *(const float4*)(s + 4);
        }
#pragma unroll
        for (int i = 0; i < 4; ++i) {
            int idx = i * 256 + t;
            int r = idx >> 4, c8 = idx & 15;
            bf16x8 v;
            v[0] = (__bf16)pf[2*i].x;   v[1] = (__bf16)pf[2*i].y;
            v[2] = (__bf16)pf[2*i].z;   v[3] = (__bf16)pf[2*i].w;
            v[4] = (__bf16)pf[2*i+1].x; v[5] = (__bf16)pf[2*i+1].y;
            v[6] = (__bf16)pf[2*i+1].z; v[7] = (__bf16)pf[2*i+1].w;
            int tile = (r >> 4) * 4 + (c8 >> 2);
            int s2 = (r & 15) + 16 * (c8 & 3);
            int phys = s2 ^ (((s2 >> 3) ^ tile) & 7);
            *(bf16x8*)&xf[0][tile * 64 + phys] = v;
        }
    }
    __syncthreads();

    // ---- tile loop ----
    for (int tt = 0; tt < TILES; ++tt) {
        const int cur = tt & 1;
        const size_t trow0 = row0 + (size_t)tt * TROWS;

        // prefetch next tile's X rows into registers (hidden under L1 MFMAs)
        if (tt + 1 < TILES) {
            const float* nsrc = nodes + (trow0 + TROWS) * HH;
#pragma unroll
            for (int i = 0; i < 4; ++i) {
                int idx = i * 256 + t;
                const float* s = nsrc + (size_t)(idx >> 4) * HH + 8 * (idx & 15);
                pf[2 * i]     = *(const float4*)s;
                pf[2 * i + 1] = *(const float4*)(s + 4);
            }
        }

        // ---- layer 1 (X K-half only; newn half pre-folded in accn) ----
        f32x4 acc[4][4];
#pragma unroll
        for (int mt = 0; mt < 4; ++mt)
#pragma unroll
            for (int nt = 0; nt < 4; ++nt) acc[mt][nt] = accn[mt];
#pragma unroll
        for (int ks = 0; ks < 4; ++ks) {
            bf16x8 af[4];
#pragma unroll
            for (int mt = 0; mt < 4; ++mt)
                af[mt] = *(const bf16x8*)(w1f + ((size_t)((4 * w + mt) * 8 + ks) * 64 + l) * 8);
#pragma unroll
            for (int nt = 0; nt < 4; ++nt) {
                int tile = nt * 4 + ks;
                int phys = l ^ (((l >> 3) ^ tile) & 7);
                bf16x8 xv = *(const bf16x8*)&xf[cur][tile * 64 + phys];
#pragma unroll
                for (int mt = 0; mt < 4; ++mt)
                    acc[mt][nt] = __builtin_amdgcn_mfma_f32_16x16x32_bf16(af[mt], xv, acc[mt][nt], 0, 0, 0);
            }
        }

        // ---- h1 writeback: relu + cvt, packed b64 by kslot, unit swizzle ----
#pragma unroll
        for (int mt = 0; mt < 4; ++mt) {
            int g = 4 * w + mt;
            int u = 4 * (g & 7) + q;
            int half = (g >> 3) & 1;
#pragma unroll
            for (int nt = 0; nt < 4; ++nt) {
                int row = 16 * nt + ln;
                bf16x4 hv;
#pragma unroll
                for (int r2 = 0; r2 < 4; ++r2)
                    hv[r2] = (__bf16)fmaxf(acc[mt][nt][r2], 0.0f);
                uint2* p = (uint2*)&h1f[row * 32 + (u ^ (row & 7))];
                p[half] = *(uint2*)&hv;
            }
        }
        __syncthreads();

        // ---- layer 2: h2^T = W2^T . h1^T, wave w -> rows 16w..16w+15 ----
        f32x4 acc2[4];
#pragma unroll
        for (int mt2 = 0; mt2 < 4; ++mt2) {
            float4 bv = *(const float4*)(b2 + 16 * mt2 + 4 * q);
            acc2[mt2][0] = bv.x; acc2[mt2][1] = bv.y; acc2[mt2][2] = bv.z; acc2[mt2][3] = bv.w;
        }
        {
            int row = 16 * w + ln;
            int rx = row & 7;
#pragma unroll
            for (int ksp = 0; ksp < 8; ++ksp) {
                bf16x8 hb = *(const bf16x8*)&h1f[row * 32 + ((4 * ksp + q) ^ rx)];
#pragma unroll
                for (int mt2 = 0; mt2 < 4; ++mt2) {
                    bf16x8 a2 = *(const bf16x8*)(w2f + ((size_t)(mt2 * 8 + ksp) * 64 + l) * 8);
                    acc2[mt2] = __builtin_amdgcn_mfma_f32_16x16x32_bf16(a2, hb, acc2[mt2], 0, 0, 0);
                }
            }
        }

        // ---- layer 3 epilogue: relu . W3, reduce over 4 q-groups, sigmoid ----
        float sum = 0.f;
#pragma unroll
        for (int mt2 = 0; mt2 < 4; ++mt2) {
            float4 w3v = *(const float4*)(W3 + 16 * mt2 + 4 * q);
            sum += fmaxf(acc2[mt2][0], 0.f) * w3v.x + fmaxf(acc2[mt2][1], 0.f) * w3v.y
                 + fmaxf(acc2[mt2][2], 0.f) * w3v.z + fmaxf(acc2[mt2][3], 0.f) * w3v.w;
        }
        sum += __shfl_xor(sum, 16, 64);
        sum += __shfl_xor(sum, 32, 64);
        if (q == 0) {
            float v = sum + b3[0];
            out[trow0 + 16 * w + ln] = 1.0f / (1.0f + __expf(-v));
        }

        // ---- write prefetched X into the other buffer ----
        if (tt + 1 < TILES) {
#pragma unroll
            for (int i = 0; i < 4; ++i) {
                int idx = i * 256 + t;
                int r = idx >> 4, c8 = idx & 15;
                bf16x8 v;
                v[0] = (__bf16)pf[2*i].x;   v[1] = (__bf16)pf[2*i].y;
                v[2] = (__bf16)pf[2*i].z;   v[3] = (__bf16)pf[2*i].w;
                v[4] = (__bf16)pf[2*i+1].x; v[5] = (__bf16)pf[2*i+1].y;
                v[6] = (__bf16)pf[2*i+1].z; v[7] = (__bf16)pf[2*i+1].w;
                int tile = (r >> 4) * 4 + (c8 >> 2);
                int s2 = (r & 15) + 16 * (c8 & 3);
                int phys = s2 ^ (((s2 >> 3) ^ tile) & 7);
                *(bf16x8*)&xf[cur ^ 1][tile * 64 + phys] = v;
            }
            __syncthreads();   // next X buffer ready; h1f free for next tile
        }
    }
}

// ---------------------------------------------------------------------------
// fp32 fallback if workspace is too small for weight frags
// ---------------------------------------------------------------------------
__global__ __launch_bounds__(256, 4) void edge_mlp_f32(
    const float* __restrict__ nodes, const float* __restrict__ newn,
    const float* __restrict__ W1, const float* __restrict__ b1,
    const float* __restrict__ W2, const float* __restrict__ b2,
    const float* __restrict__ W3, const float* __restrict__ b3,
    float* __restrict__ out)
{
    __shared__ float buf[32][256];
    const int t = threadIdx.x;
    const long r0 = (long)blockIdx.x * 32;
    const int b = (int)(r0 >> 12);
    const float4* src = (const float4*)(nodes + (size_t)r0 * HH);
#pragma unroll
    for (int i = 0; i < 4; ++i) {
        int idx = t + i * 256;
        *(float4*)&buf[idx >> 5][(idx & 31) * 4] = src[idx];
    }
    {
        float nv = newn[b * HH + (t & 127)];
        for (int r = (t >> 7); r < 32; r += 2) buf[r][HH + (t & 127)] = nv;
    }
    __syncthreads();
    const int c0 = t & 63, rb = (t >> 6) * 8;
    float acc[8][4];
#pragma unroll
    for (int ci = 0; ci < 4; ++ci) {
        float bv = b1[c0 + 64 * ci];
#pragma unroll
        for (int r = 0; r < 8; ++r) acc[r][ci] = bv;
    }
    for (int k = 0; k < 256; k += 4) {
        float wv[4][4];
#pragma unroll
        for (int kk = 0; kk < 4; ++kk)
#pragma unroll
            for (int ci = 0; ci < 4; ++ci) wv[kk][ci] = W1[(k + kk) * N1 + c0 + 64 * ci];
#pragma unroll
        for (int r = 0; r < 8; ++r) {
            float4 x = *(const float4*)&buf[rb + r][k];
#pragma unroll
            for (int ci = 0; ci < 4; ++ci) {
                acc[r][ci] = fmaf(x.x, wv[0][ci], acc[r][ci]);
                acc[r][ci] = fmaf(x.y, wv[1][ci], acc[r][ci]);
                acc[r][ci] = fmaf(x.z, wv[2][ci], acc[r][ci]);
                acc[r][ci] = fmaf(x.w, wv[3][ci], acc[r][ci]);
            }
        }
    }
    __syncthreads();
#pragma unroll
    for (int r = 0; r < 8; ++r)
#pragma unroll
        for (int ci = 0; ci < 4; ++ci) buf[rb + r][c0 + 64 * ci] = fmaxf(acc[r][ci], 0.0f);
    __syncthreads();
    const int c2 = t & 31, g2 = t >> 5;
    float acc2[4][2];
#pragma unroll
    for (int cj = 0; cj < 2; ++cj) {
        float bv = b2[c2 + 32 * cj];
#pragma unroll
        for (int rr = 0; rr < 4; ++rr) acc2[rr][cj] = bv;
    }
    for (int k = 0; k < 256; k += 4) {
        float w2v[4][2];
#pragma unroll
        for (int kk = 0; kk < 4; ++kk)
#pragma unroll
            for (int cj = 0; cj < 2; ++cj) w2v[kk][cj] = W2[(k + kk) * N2 + c2 + 32 * cj];
#pragma unroll
        for (int rr = 0; rr < 4; ++rr) {
            float4 x = *(const float4*)&buf[4 * g2 + rr][k];
#pragma unroll
            for (int cj = 0; cj < 2; ++cj) {
                acc2[rr][cj] = fmaf(x.x, w2v[0][cj], acc2[rr][cj]);
                acc2[rr][cj] = fmaf(x.y, w2v[1][cj], acc2[rr][cj]);
                acc2[rr][cj] = fmaf(x.z, w2v[2][cj], acc2[rr][cj]);
                acc2[rr][cj] = fmaf(x.w, w2v[3][cj], acc2[rr][cj]);
            }
        }
    }
    const float w3a = W3[c2], w3b = W3[c2 + 32], b3v = b3[0];
    float p[4];
#pragma unroll
    for (int rr = 0; rr < 4; ++rr)
        p[rr] = fmaf(fmaxf(acc2[rr][0], 0.f), w3a, fmaxf(acc2[rr][1], 0.f) * w3b);
#pragma unroll
    for (int off = 16; off >= 1; off >>= 1)
#pragma unroll
        for (int rr = 0; rr < 4; ++rr) p[rr] += __shfl_xor(p[rr], off, 64);
    if (c2 == 0)
#pragma unroll
        for (int rr = 0; rr < 4; ++rr)
            out[r0 + 4 * g2 + rr] = 1.0f / (1.0f + __expf(-(p[rr] + b3v)));
}

extern "C" void kernel_launch(void* const* d_in, const int* in_sizes, int n_in,
                              void* d_out, int out_size, void* d_ws, size_t ws_size,
                              hipStream_t stream) {
    const float* nodes = (const float*)d_in[0];
    const float* newn  = (const float*)d_in[1];
    const float* W1    = (const float*)d_in[2];
    const float* b1    = (const float*)d_in[3];
    const float* W2    = (const float*)d_in[4];
    const float* b2    = (const float*)d_in[5];
    const float* W3    = (const float*)d_in[6];
    const float* b3    = (const float*)d_in[7];
    float* out = (float*)d_out;
    const int M = BB * SS;

    if (ws_size >= 163840) {
        __bf16* w1f = (__bf16*)d_ws;
        __bf16* w2f = (__bf16*)d_ws + 65536;   // 128 KB in
        hipLaunchKernelGGL(conv_weights, dim3(40), dim3(256), 0, stream, W1, W2, w1f, w2f);
        hipLaunchKernelGGL(edge_mlp_mfma2, dim3(M / BROWS), dim3(256), 0, stream,
                           nodes, newn, b1, b2, W3, b3, w1f, w2f, out);
    } else {
        hipLaunchKernelGGL(edge_mlp_f32, dim3(M / 32), dim3(256), 0, stream,
                           nodes, newn, W1, b1, W2, b2, W3, b3, out);
    }
}

// Round 4
// 120.670 us; speedup vs baseline: 2.7176x; 2.7176x over previous
//
#include <hip/hip_runtime.h>
#include <hip/hip_bf16.h>
#include <cstdint>
#include <cstddef>

#define BB 128
#define SS 4096
#define HH 128
#define N1 256
#define N2 64
#define BROWS 256   // rows per block = 4 waves * 64 rows; 256 | 4096 -> one b per block

typedef __bf16 bf16x8 __attribute__((ext_vector_type(8)));
typedef float  f32x4  __attribute__((ext_vector_type(4)));

// ---------------------------------------------------------------------------
// Prologue.
// w1f: A-frags of W1^T (== B-frags of W1), frag(g 0..15, ks 0..7):
//   val[l][j] = W1[32ks + 8*(l>>4) + j][16g + (l&15)]
//   (ks 0..3 = nodes half, ks 4..7 = newn half)
// w2f: A-frags of W2^T with the n-split k-slot relabel. kslot (ksp, q, j) is
//   assigned h1-col c = 32ksp + 16*(j>>2) + 4q + (j&3), which is exactly what
//   lane (q,ln) holds in its L1 C/D regs for g-pair (2ksp, 2ksp+1):
//   acc_lo reg r <-> c = 32ksp+4q+r, acc_hi reg r <-> c = 32ksp+16+4q+r.
//   frag(mt2 0..3, ksp 0..7): val[l][j] = W2[c(ksp, l>>4, j)][16mt2 + (l&15)]
// ---------------------------------------------------------------------------
__global__ __launch_bounds__(256) void conv_weights(
    const float* __restrict__ W1, const float* __restrict__ W2,
    __bf16* __restrict__ w1f, __bf16* __restrict__ w2f)
{
    int tid = blockIdx.x * 256 + threadIdx.x;
    if (tid < 8192) {
        int lane = tid & 63, ks = (tid >> 6) & 7, g = tid >> 9;
        int col = 16 * g + (lane & 15);
        int kbase = 32 * ks + 8 * (lane >> 4);
        bf16x8 v;
#pragma unroll
        for (int j = 0; j < 8; ++j) v[j] = (__bf16)W1[(size_t)(kbase + j) * N1 + col];
        *(bf16x8*)(w1f + (size_t)tid * 8) = v;
    } else if (tid < 10240) {
        int s = tid - 8192;
        int lane = s & 63, ksp = (s >> 6) & 7, mt2 = s >> 9;
        int q = lane >> 4, ln = lane & 15;
        bf16x8 v;
#pragma unroll
        for (int j = 0; j < 8; ++j) {
            int c = 32 * ksp + 16 * (j >> 2) + 4 * q + (j & 3);
            v[j] = (__bf16)W2[(size_t)c * N2 + 16 * mt2 + ln];
        }
        *(bf16x8*)(w2f + (size_t)s * 8) = v;
    }
}

// ---------------------------------------------------------------------------
// Main kernel, n-split: 4 waves, wave w owns sample rows 64w..64w+63 (4 row-
// sets of 16). Per ks' (g-pair): load W1/W2 A-frags from global (L2-hot),
// recompute newn+bias partial (accn) with 8 MFMAs, then per rowset run the
// nodes-half L1 (8 MFMAs), relabel C/D regs directly into the layer-2 B-frag
// (relu + cvt, zero cross-lane traffic), and accumulate h2 (4 MFMAs).
// X tile lives in LDS [256][128] bf16 with a 16B-unit XOR swizzle
// (unit ^= row&7) making both staging writes and frag reads bank-balanced.
// One barrier per block. No h1 LDS roundtrip. Nothing large persists in
// VGPRs except acc2 (64) + nfrag (16).
// ---------------------------------------------------------------------------
__global__ __launch_bounds__(256, 2) void edge_mlp_mfma3(
    const float* __restrict__ nodes, const float* __restrict__ newn,
    const float* __restrict__ b1, const float* __restrict__ b2,
    const float* __restrict__ W3, const float* __restrict__ b3,
    const __bf16* __restrict__ w1f, const __bf16* __restrict__ w2f,
    float* __restrict__ out)
{
    __shared__ __bf16 X[BROWS * HH];   // 64 KB

    const int t = threadIdx.x;
    const int w = t >> 6, l = t & 63, q = l >> 4, ln = l & 15;
    const int rx = ln & 7;
    const size_t row0 = (size_t)blockIdx.x * BROWS;
    const int b = (int)(row0 >> 12);

    // ---- newn B-frags (k-offsets within the newn 128-half), lane-row indep.
    bf16x8 nfrag[4];
#pragma unroll
    for (int ks = 0; ks < 4; ++ks) {
        const float* np = newn + b * HH + 32 * ks + 8 * q;
        float4 f0 = *(const float4*)np, f1 = *(const float4*)(np + 4);
        nfrag[ks][0] = (__bf16)f0.x; nfrag[ks][1] = (__bf16)f0.y;
        nfrag[ks][2] = (__bf16)f0.z; nfrag[ks][3] = (__bf16)f0.w;
        nfrag[ks][4] = (__bf16)f1.x; nfrag[ks][5] = (__bf16)f1.y;
        nfrag[ks][6] = (__bf16)f1.z; nfrag[ks][7] = (__bf16)f1.w;
    }

    // ---- stage X: 256 rows x 128 cols f32 -> bf16 LDS, unit-swizzled ----
#pragma unroll
    for (int i = 0; i < 16; ++i) {
        int idx = i * 256 + t;
        int r = idx >> 4, c8 = idx & 15;
        const float* s = nodes + (row0 + r) * HH + 8 * c8;
        float4 f0 = *(const float4*)s, f1 = *(const float4*)(s + 4);
        bf16x8 v;
        v[0] = (__bf16)f0.x; v[1] = (__bf16)f0.y; v[2] = (__bf16)f0.z; v[3] = (__bf16)f0.w;
        v[4] = (__bf16)f1.x; v[5] = (__bf16)f1.y; v[6] = (__bf16)f1.z; v[7] = (__bf16)f1.w;
        int unit = c8 ^ (r & 7);
        *(bf16x8*)&X[(size_t)(r * 16 + unit) * 8] = v;
    }
    __syncthreads();

    // ---- h2 accumulators: [rowset][mt2], bias-initialized ----
    f32x4 acc2[4][4];
#pragma unroll
    for (int mt2 = 0; mt2 < 4; ++mt2) {
        float4 bv = *(const float4*)(b2 + 16 * mt2 + 4 * q);
#pragma unroll
        for (int rs = 0; rs < 4; ++rs) {
            acc2[rs][mt2][0] = bv.x; acc2[rs][mt2][1] = bv.y;
            acc2[rs][mt2][2] = bv.z; acc2[rs][mt2][3] = bv.w;
        }
    }

    // ---- main loop over g-pairs / layer-2 k-steps ----
#pragma unroll 1
    for (int ksp = 0; ksp < 8; ++ksp) {
        // W1 A-frags (nodes half) for g = 2ksp, 2ksp+1
        bf16x8 af0[4], af1[4], a2f[4];
#pragma unroll
        for (int ks = 0; ks < 4; ++ks) {
            af0[ks] = *(const bf16x8*)(w1f + ((size_t)((2 * ksp)     * 8 + ks) * 64 + l) * 8);
            af1[ks] = *(const bf16x8*)(w1f + ((size_t)((2 * ksp + 1) * 8 + ks) * 64 + l) * 8);
        }
#pragma unroll
        for (int mt2 = 0; mt2 < 4; ++mt2)
            a2f[mt2] = *(const bf16x8*)(w2f + ((size_t)(mt2 * 8 + ksp) * 64 + l) * 8);

        // accn = b1 + W1^T(newn half) . newn  (row-independent partial)
        f32x4 an0, an1;
        {
            float4 v0 = *(const float4*)(b1 + 32 * ksp + 4 * q);
            float4 v1 = *(const float4*)(b1 + 32 * ksp + 16 + 4 * q);
            an0[0] = v0.x; an0[1] = v0.y; an0[2] = v0.z; an0[3] = v0.w;
            an1[0] = v1.x; an1[1] = v1.y; an1[2] = v1.z; an1[3] = v1.w;
        }
#pragma unroll
        for (int ks = 0; ks < 4; ++ks) {
            bf16x8 fn0 = *(const bf16x8*)(w1f + ((size_t)((2 * ksp)     * 8 + 4 + ks) * 64 + l) * 8);
            bf16x8 fn1 = *(const bf16x8*)(w1f + ((size_t)((2 * ksp + 1) * 8 + 4 + ks) * 64 + l) * 8);
            an0 = __builtin_amdgcn_mfma_f32_16x16x32_bf16(fn0, nfrag[ks], an0, 0, 0, 0);
            an1 = __builtin_amdgcn_mfma_f32_16x16x32_bf16(fn1, nfrag[ks], an1, 0, 0, 0);
        }

        // per rowset: nodes-half L1, register relabel -> L2 B-frag, L2 MFMAs
#pragma unroll
        for (int rs = 0; rs < 4; ++rs) {
            f32x4 alo = an0, ahi = an1;
            const int r = 64 * w + 16 * rs + ln;
#pragma unroll
            for (int ks = 0; ks < 4; ++ks) {
                bf16x8 xv = *(const bf16x8*)&X[(size_t)(r * 16 + ((4 * ks + q) ^ rx)) * 8];
                alo = __builtin_amdgcn_mfma_f32_16x16x32_bf16(af0[ks], xv, alo, 0, 0, 0);
                ahi = __builtin_amdgcn_mfma_f32_16x16x32_bf16(af1[ks], xv, ahi, 0, 0, 0);
            }
            bf16x8 bfrag;
#pragma unroll
            for (int j = 0; j < 4; ++j) {
                bfrag[j]     = (__bf16)fmaxf(alo[j], 0.0f);
                bfrag[4 + j] = (__bf16)fmaxf(ahi[j], 0.0f);
            }
#pragma unroll
            for (int mt2 = 0; mt2 < 4; ++mt2)
                acc2[rs][mt2] = __builtin_amdgcn_mfma_f32_16x16x32_bf16(a2f[mt2], bfrag, acc2[rs][mt2], 0, 0, 0);
        }
    }

    // ---- layer 3: relu(h2).W3 + b3, reduce over q-groups, sigmoid ----
    const float b3v = b3[0];
#pragma unroll
    for (int rs = 0; rs < 4; ++rs) {
        float sum = 0.f;
#pragma unroll
        for (int mt2 = 0; mt2 < 4; ++mt2) {
            float4 w3v = *(const float4*)(W3 + 16 * mt2 + 4 * q);
            sum += fmaxf(acc2[rs][mt2][0], 0.f) * w3v.x
                 + fmaxf(acc2[rs][mt2][1], 0.f) * w3v.y
                 + fmaxf(acc2[rs][mt2][2], 0.f) * w3v.z
                 + fmaxf(acc2[rs][mt2][3], 0.f) * w3v.w;
        }
        sum += __shfl_xor(sum, 16, 64);
        sum += __shfl_xor(sum, 32, 64);
        if (q == 0) {
            float v = sum + b3v;
            out[row0 + 64 * w + 16 * rs + ln] = 1.0f / (1.0f + __expf(-v));
        }
    }
}

// ---------------------------------------------------------------------------
// fp32 fallback if workspace is too small for weight frags
// ---------------------------------------------------------------------------
__global__ __launch_bounds__(256, 4) void edge_mlp_f32(
    const float* __restrict__ nodes, const float* __restrict__ newn,
    const float* __restrict__ W1, const float* __restrict__ b1,
    const float* __restrict__ W2, const float* __restrict__ b2,
    const float* __restrict__ W3, const float* __restrict__ b3,
    float* __restrict__ out)
{
    __shared__ float buf[32][256];
    const int t = threadIdx.x;
    const long r0 = (long)blockIdx.x * 32;
    const int b = (int)(r0 >> 12);
    const float4* src = (const float4*)(nodes + (size_t)r0 * HH);
#pragma unroll
    for (int i = 0; i < 4; ++i) {
        int idx = t + i * 256;
        *(float4*)&buf[idx >> 5][(idx & 31) * 4] = src[idx];
    }
    {
        float nv = newn[b * HH + (t & 127)];
        for (int r = (t >> 7); r < 32; r += 2) buf[r][HH + (t & 127)] = nv;
    }
    __syncthreads();
    const int c0 = t & 63, rb = (t >> 6) * 8;
    float acc[8][4];
#pragma unroll
    for (int ci = 0; ci < 4; ++ci) {
        float bv = b1[c0 + 64 * ci];
#pragma unroll
        for (int r = 0; r < 8; ++r) acc[r][ci] = bv;
    }
    for (int k = 0; k < 256; k += 4) {
        float wv[4][4];
#pragma unroll
        for (int kk = 0; kk < 4; ++kk)
#pragma unroll
            for (int ci = 0; ci < 4; ++ci) wv[kk][ci] = W1[(k + kk) * N1 + c0 + 64 * ci];
#pragma unroll
        for (int r = 0; r < 8; ++r) {
            float4 x = *(const float4*)&buf[rb + r][k];
#pragma unroll
            for (int ci = 0; ci < 4; ++ci) {
                acc[r][ci] = fmaf(x.x, wv[0][ci], acc[r][ci]);
                acc[r][ci] = fmaf(x.y, wv[1][ci], acc[r][ci]);
                acc[r][ci] = fmaf(x.z, wv[2][ci], acc[r][ci]);
                acc[r][ci] = fmaf(x.w, wv[3][ci], acc[r][ci]);
            }
        }
    }
    __syncthreads();
#pragma unroll
    for (int r = 0; r < 8; ++r)
#pragma unroll
        for (int ci = 0; ci < 4; ++ci) buf[rb + r][c0 + 64 * ci] = fmaxf(acc[r][ci], 0.0f);
    __syncthreads();
    const int c2 = t & 31, g2 = t >> 5;
    float acc2[4][2];
#pragma unroll
    for (int cj = 0; cj < 2; ++cj) {
        float bv = b2[c2 + 32 * cj];
#pragma unroll
        for (int rr = 0; rr < 4; ++rr) acc2[rr][cj] = bv;
    }
    for (int k = 0; k < 256; k += 4) {
        float w2v[4][2];
#pragma unroll
        for (int kk = 0; kk < 4; ++kk)
#pragma unroll
            for (int cj = 0; cj < 2; ++cj) w2v[kk][cj] = W2[(k + kk) * N2 + c2 + 32 * cj];
#pragma unroll
        for (int rr = 0; rr < 4; ++rr) {
            float4 x = *(const float4*)&buf[4 * g2 + rr][k];
#pragma unroll
            for (int cj = 0; cj < 2; ++cj) {
                acc2[rr][cj] = fmaf(x.x, w2v[0][cj], acc2[rr][cj]);
                acc2[rr][cj] = fmaf(x.y, w2v[1][cj], acc2[rr][cj]);
                acc2[rr][cj] = fmaf(x.z, w2v[2][cj], acc2[rr][cj]);
                acc2[rr][cj] = fmaf(x.w, w2v[3][cj], acc2[rr][cj]);
            }
        }
    }
    const float w3a = W3[c2], w3b = W3[c2 + 32], b3v = b3[0];
    float p[4];
#pragma unroll
    for (int rr = 0; rr < 4; ++rr)
        p[rr] = fmaf(fmaxf(acc2[rr][0], 0.f), w3a, fmaxf(acc2[rr][1], 0.f) * w3b);
#pragma unroll
    for (int off = 16; off >= 1; off >>= 1)
#pragma unroll
        for (int rr = 0; rr < 4; ++rr) p[rr] += __shfl_xor(p[rr], off, 64);
    if (c2 == 0)
#pragma unroll
        for (int rr = 0; rr < 4; ++rr)
            out[r0 + 4 * g2 + rr] = 1.0f / (1.0f + __expf(-(p[rr] + b3v)));
}

extern "C" void kernel_launch(void* const* d_in, const int* in_sizes, int n_in,
                              void* d_out, int out_size, void* d_ws, size_t ws_size,
                              hipStream_t stream) {
    const float* nodes = (const float*)d_in[0];
    const float* newn  = (const float*)d_in[1];
    const float* W1    = (const float*)d_in[2];
    const float* b1    = (const float*)d_in[3];
    const float* W2    = (const float*)d_in[4];
    const float* b2    = (const float*)d_in[5];
    const float* W3    = (const float*)d_in[6];
    const float* b3    = (const float*)d_in[7];
    float* out = (float*)d_out;
    const int M = BB * SS;

    if (ws_size >= 163840) {
        __bf16* w1f = (__bf16*)d_ws;                 // 128 KB
        __bf16* w2f = (__bf16*)d_ws + 65536;         // +32 KB
        hipLaunchKernelGGL(conv_weights, dim3(40), dim3(256), 0, stream, W1, W2, w1f, w2f);
        hipLaunchKernelGGL(edge_mlp_mfma3, dim3(M / BROWS), dim3(256), 0, stream,
                           nodes, newn, b1, b2, W3, b3, w1f, w2f, out);
    } else {
        hipLaunchKernelGGL(edge_mlp_f32, dim3(M / 32), dim3(256), 0, stream,
                           nodes, newn, W1, b1, W2, b2, W3, b3, out);
    }
}

// Round 5
// 97.756 us; speedup vs baseline: 3.3546x; 1.2344x over previous
//
#include <hip/hip_runtime.h>
#include <hip/hip_bf16.h>
#include <cstdint>
#include <cstddef>

#define BB 128
#define SS 4096
#define HH 128
#define N1 256
#define N2 64
#define BROWS 128   // rows per block; 128 | 4096 -> one b per block

typedef __bf16 bf16x8 __attribute__((ext_vector_type(8)));
typedef __bf16 bf16x4 __attribute__((ext_vector_type(4)));
typedef float  f32x4  __attribute__((ext_vector_type(4)));

// ---------------------------------------------------------------------------
// Prologue 1: weight frags.
// w1f (nodes half only, 64 KB): frag(g 0..15, ks 0..3):
//   val[l][j] = W1[32ks + 8*(l>>4) + j][16g + (l&15)]
// w2f (32 KB): A-frags of W2^T with the n-split k-slot relabel:
//   frag(mt2 0..3, ksp 0..7): val[l][j] = W2[c][16mt2 + (l&15)],
//   c = 32ksp + 16*(j>>2) + 4*(l>>4) + (j&3)
// (relabel verified in round 4: lane (q,ln)'s L1 C/D regs for g-pair
//  (2ksp,2ksp+1) are exactly k-slots (ksp, q, j) of the layer-2 B operand)
// ---------------------------------------------------------------------------
__global__ __launch_bounds__(256) void conv_weights(
    const float* __restrict__ W1, const float* __restrict__ W2,
    __bf16* __restrict__ w1f, __bf16* __restrict__ w2f)
{
    int tid = blockIdx.x * 256 + threadIdx.x;
    if (tid < 4096) {                        // W1 nodes half: 16 g * 4 ks * 64 lanes
        int lane = tid & 63, ks = (tid >> 6) & 3, g = tid >> 8;
        int col = 16 * g + (lane & 15);
        int kbase = 32 * ks + 8 * (lane >> 4);
        bf16x8 v;
#pragma unroll
        for (int j = 0; j < 8; ++j) v[j] = (__bf16)W1[(size_t)(kbase + j) * N1 + col];
        *(bf16x8*)(w1f + (size_t)tid * 8) = v;
    } else if (tid < 6144) {                 // W2: 4 mt2 * 8 ksp * 64 lanes
        int s = tid - 4096;
        int lane = s & 63, ksp = (s >> 6) & 7, mt2 = s >> 9;
        int q = lane >> 4, ln = lane & 15;
        bf16x8 v;
#pragma unroll
        for (int j = 0; j < 8; ++j) {
            int c = 32 * ksp + 16 * (j >> 2) + 4 * q + (j & 3);
            v[j] = (__bf16)W2[(size_t)c * N2 + 16 * mt2 + ln];
        }
        *(bf16x8*)(w2f + (size_t)s * 8) = v;
    }
}

// ---------------------------------------------------------------------------
// Prologue 2: an[b][c] = b1[c] + newn[b,:] . W1[128:256, c]  (f32 math, bf16
// store). Row-independent layer-1 partial; removes all per-wave newn MFMAs.
// ---------------------------------------------------------------------------
__global__ __launch_bounds__(256) void an_partial(
    const float* __restrict__ W1, const float* __restrict__ b1,
    const float* __restrict__ newn, __bf16* __restrict__ an)
{
    const int b = blockIdx.x, c = threadIdx.x;
    float acc = b1[c];
    const float* wp = W1 + (size_t)HH * N1 + c;   // rows 128..255, col c
    const float* nv = newn + (size_t)b * HH;
#pragma unroll 8
    for (int k = 0; k < HH; ++k)
        acc = fmaf(nv[k], wp[(size_t)k * N1], acc);
    an[(size_t)b * N1 + c] = (__bf16)acc;
}

// ---------------------------------------------------------------------------
// Main kernel. 4 waves; wave w owns sample rows 32w..32w+31 (2 rowsets of 16).
// X tile [128][128] bf16 in LDS (32 KB), 16B-unit XOR swizzle (unit ^= r&7):
// both staging writes and frag reads hit the 8-lanes-per-quad-bank floor.
// Per ksp (g-pair / layer-2 k-step): 12 global frag loads (L2-hot) + an
// broadcast load, then per rowset: 8 L1 MFMAs -> register relu/cvt relabel
// -> 4 L2 MFMAs. One barrier per block; no h1 LDS roundtrip; no per-wave
// newn MFMAs. launch_bounds(256,4): VGPR<=128 -> 4 blocks/CU, 4 waves/SIMD.
// ---------------------------------------------------------------------------
__global__ __launch_bounds__(256, 4) void edge_mlp_mfma4(
    const float* __restrict__ nodes,
    const float* __restrict__ b2,
    const float* __restrict__ W3, const float* __restrict__ b3,
    const __bf16* __restrict__ w1f, const __bf16* __restrict__ w2f,
    const __bf16* __restrict__ an,
    float* __restrict__ out)
{
    __shared__ __bf16 X[BROWS * HH];   // 32 KB

    const int t = threadIdx.x;
    const int w = t >> 6, l = t & 63, q = l >> 4, ln = l & 15;
    const size_t row0 = (size_t)blockIdx.x * BROWS;
    const int b = (int)(row0 >> 12);

    // ---- stage X: 128 rows x 128 cols f32 -> bf16 LDS, unit-swizzled ----
#pragma unroll
    for (int i = 0; i < 8; ++i) {
        int idx = i * 256 + t;             // 0..2047 (row, 8-col chunk)
        int r = idx >> 4, c8 = idx & 15;
        const float* s = nodes + (row0 + r) * HH + 8 * c8;
        float4 f0 = *(const float4*)s, f1 = *(const float4*)(s + 4);
        bf16x8 v;
        v[0] = (__bf16)f0.x; v[1] = (__bf16)f0.y; v[2] = (__bf16)f0.z; v[3] = (__bf16)f0.w;
        v[4] = (__bf16)f1.x; v[5] = (__bf16)f1.y; v[6] = (__bf16)f1.z; v[7] = (__bf16)f1.w;
        int unit = c8 ^ (r & 7);
        *(bf16x8*)&X[(size_t)(r * 16 + unit) * 8] = v;
    }
    __syncthreads();

    // ---- h2 accumulators [rowset][mt2], bias-initialized ----
    f32x4 acc2[2][4];
#pragma unroll
    for (int mt2 = 0; mt2 < 4; ++mt2) {
        float4 bv = *(const float4*)(b2 + 16 * mt2 + 4 * q);
#pragma unroll
        for (int rs = 0; rs < 2; ++rs) {
            acc2[rs][mt2][0] = bv.x; acc2[rs][mt2][1] = bv.y;
            acc2[rs][mt2][2] = bv.z; acc2[rs][mt2][3] = bv.w;
        }
    }

    const __bf16* anb = an + (size_t)b * N1;

    // ---- main loop over g-pairs / layer-2 k-steps ----
#pragma unroll 1
    for (int ksp = 0; ksp < 8; ++ksp) {
        bf16x8 af0[4], af1[4], a2f[4];
#pragma unroll
        for (int ks = 0; ks < 4; ++ks) {
            af0[ks] = *(const bf16x8*)(w1f + ((size_t)((2 * ksp)     * 4 + ks) * 64 + l) * 8);
            af1[ks] = *(const bf16x8*)(w1f + ((size_t)((2 * ksp + 1) * 4 + ks) * 64 + l) * 8);
        }
#pragma unroll
        for (int mt2 = 0; mt2 < 4; ++mt2)
            a2f[mt2] = *(const bf16x8*)(w2f + ((size_t)(mt2 * 8 + ksp) * 64 + l) * 8);

        // newn+bias partial for this g-pair: broadcast 8B loads, cvt to f32
        f32x4 an0, an1;
        {
            bf16x4 a0 = *(const bf16x4*)(anb + 32 * ksp + 4 * q);
            bf16x4 a1 = *(const bf16x4*)(anb + 32 * ksp + 16 + 4 * q);
#pragma unroll
            for (int j = 0; j < 4; ++j) { an0[j] = (float)a0[j]; an1[j] = (float)a1[j]; }
        }

#pragma unroll
        for (int rs = 0; rs < 2; ++rs) {
            const int r = 32 * w + 16 * rs + ln;
            const int rx = ln & 7;        // r&7 == ln&7 (32w+16rs is 8-aligned)
            f32x4 alo = an0, ahi = an1;
#pragma unroll
            for (int ks = 0; ks < 4; ++ks) {
                bf16x8 xv = *(const bf16x8*)&X[(size_t)(r * 16 + ((4 * ks + q) ^ rx)) * 8];
                alo = __builtin_amdgcn_mfma_f32_16x16x32_bf16(af0[ks], xv, alo, 0, 0, 0);
                ahi = __builtin_amdgcn_mfma_f32_16x16x32_bf16(af1[ks], xv, ahi, 0, 0, 0);
            }
            bf16x8 bfrag;
#pragma unroll
            for (int j = 0; j < 4; ++j) {
                bfrag[j]     = (__bf16)fmaxf(alo[j], 0.0f);
                bfrag[4 + j] = (__bf16)fmaxf(ahi[j], 0.0f);
            }
#pragma unroll
            for (int mt2 = 0; mt2 < 4; ++mt2)
                acc2[rs][mt2] = __builtin_amdgcn_mfma_f32_16x16x32_bf16(a2f[mt2], bfrag, acc2[rs][mt2], 0, 0, 0);
        }
    }

    // ---- layer 3: relu(h2).W3 + b3, reduce over q-groups, sigmoid ----
    const float b3v = b3[0];
#pragma unroll
    for (int rs = 0; rs < 2; ++rs) {
        float sum = 0.f;
#pragma unroll
        for (int mt2 = 0; mt2 < 4; ++mt2) {
            float4 w3v = *(const float4*)(W3 + 16 * mt2 + 4 * q);
            sum += fmaxf(acc2[rs][mt2][0], 0.f) * w3v.x
                 + fmaxf(acc2[rs][mt2][1], 0.f) * w3v.y
                 + fmaxf(acc2[rs][mt2][2], 0.f) * w3v.z
                 + fmaxf(acc2[rs][mt2][3], 0.f) * w3v.w;
        }
        sum += __shfl_xor(sum, 16, 64);
        sum += __shfl_xor(sum, 32, 64);
        if (q == 0) {
            float v = sum + b3v;
            out[row0 + 32 * w + 16 * rs + ln] = 1.0f / (1.0f + __expf(-v));
        }
    }
}

// ---------------------------------------------------------------------------
// fp32 fallback if workspace is too small
// ---------------------------------------------------------------------------
__global__ __launch_bounds__(256, 4) void edge_mlp_f32(
    const float* __restrict__ nodes, const float* __restrict__ newn,
    const float* __restrict__ W1, const float* __restrict__ b1,
    const float* __restrict__ W2, const float* __restrict__ b2,
    const float* __restrict__ W3, const float* __restrict__ b3,
    float* __restrict__ out)
{
    __shared__ float buf[32][256];
    const int t = threadIdx.x;
    const long r0 = (long)blockIdx.x * 32;
    const int b = (int)(r0 >> 12);
    const float4* src = (const float4*)(nodes + (size_t)r0 * HH);
#pragma unroll
    for (int i = 0; i < 4; ++i) {
        int idx = t + i * 256;
        *(float4*)&buf[idx >> 5][(idx & 31) * 4] = src[idx];
    }
    {
        float nv = newn[b * HH + (t & 127)];
        for (int r = (t >> 7); r < 32; r += 2) buf[r][HH + (t & 127)] = nv;
    }
    __syncthreads();
    const int c0 = t & 63, rb = (t >> 6) * 8;
    float acc[8][4];
#pragma unroll
    for (int ci = 0; ci < 4; ++ci) {
        float bv = b1[c0 + 64 * ci];
#pragma unroll
        for (int r = 0; r < 8; ++r) acc[r][ci] = bv;
    }
    for (int k = 0; k < 256; k += 4) {
        float wv[4][4];
#pragma unroll
        for (int kk = 0; kk < 4; ++kk)
#pragma unroll
            for (int ci = 0; ci < 4; ++ci) wv[kk][ci] = W1[(k + kk) * N1 + c0 + 64 * ci];
#pragma unroll
        for (int r = 0; r < 8; ++r) {
            float4 x = *(const float4*)&buf[rb + r][k];
#pragma unroll
            for (int ci = 0; ci < 4; ++ci) {
                acc[r][ci] = fmaf(x.x, wv[0][ci], acc[r][ci]);
                acc[r][ci] = fmaf(x.y, wv[1][ci], acc[r][ci]);
                acc[r][ci] = fmaf(x.z, wv[2][ci], acc[r][ci]);
                acc[r][ci] = fmaf(x.w, wv[3][ci], acc[r][ci]);
            }
        }
    }
    __syncthreads();
#pragma unroll
    for (int r = 0; r < 8; ++r)
#pragma unroll
        for (int ci = 0; ci < 4; ++ci) buf[rb + r][c0 + 64 * ci] = fmaxf(acc[r][ci], 0.0f);
    __syncthreads();
    const int c2 = t & 31, g2 = t >> 5;
    float acc2[4][2];
#pragma unroll
    for (int cj = 0; cj < 2; ++cj) {
        float bv = b2[c2 + 32 * cj];
#pragma unroll
        for (int rr = 0; rr < 4; ++rr) acc2[rr][cj] = bv;
    }
    for (int k = 0; k < 256; k += 4) {
        float w2v[4][2];
#pragma unroll
        for (int kk = 0; kk < 4; ++kk)
#pragma unroll
            for (int cj = 0; cj < 2; ++cj) w2v[kk][cj] = W2[(k + kk) * N2 + c2 + 32 * cj];
#pragma unroll
        for (int rr = 0; rr < 4; ++rr) {
            float4 x = *(const float4*)&buf[4 * g2 + rr][k];
#pragma unroll
            for (int cj = 0; cj < 2; ++cj) {
                acc2[rr][cj] = fmaf(x.x, w2v[0][cj], acc2[rr][cj]);
                acc2[rr][cj] = fmaf(x.y, w2v[1][cj], acc2[rr][cj]);
                acc2[rr][cj] = fmaf(x.z, w2v[2][cj], acc2[rr][cj]);
                acc2[rr][cj] = fmaf(x.w, w2v[3][cj], acc2[rr][cj]);
            }
        }
    }
    const float w3a = W3[c2], w3b = W3[c2 + 32], b3v = b3[0];
    float p[4];
#pragma unroll
    for (int rr = 0; rr < 4; ++rr)
        p[rr] = fmaf(fmaxf(acc2[rr][0], 0.f), w3a, fmaxf(acc2[rr][1], 0.f) * w3b);
#pragma unroll
    for (int off = 16; off >= 1; off >>= 1)
#pragma unroll
        for (int rr = 0; rr < 4; ++rr) p[rr] += __shfl_xor(p[rr], off, 64);
    if (c2 == 0)
#pragma unroll
        for (int rr = 0; rr < 4; ++rr)
            out[r0 + 4 * g2 + rr] = 1.0f / (1.0f + __expf(-(p[rr] + b3v)));
}

extern "C" void kernel_launch(void* const* d_in, const int* in_sizes, int n_in,
                              void* d_out, int out_size, void* d_ws, size_t ws_size,
                              hipStream_t stream) {
    const float* nodes = (const float*)d_in[0];
    const float* newn  = (const float*)d_in[1];
    const float* W1    = (const float*)d_in[2];
    const float* b1    = (const float*)d_in[3];
    const float* W2    = (const float*)d_in[4];
    const float* b2    = (const float*)d_in[5];
    const float* W3    = (const float*)d_in[6];
    const float* b3    = (const float*)d_in[7];
    float* out = (float*)d_out;
    const int M = BB * SS;

    if (ws_size >= 163840) {               // 64K w1f + 32K w2f + 64K an
        __bf16* w1f = (__bf16*)d_ws;                   // 32768 elems
        __bf16* w2f = (__bf16*)d_ws + 32768;           // 16384 elems
        __bf16* anp = (__bf16*)d_ws + 49152;           // 32768 elems
        hipLaunchKernelGGL(conv_weights, dim3(24), dim3(256), 0, stream, W1, W2, w1f, w2f);
        hipLaunchKernelGGL(an_partial, dim3(BB), dim3(256), 0, stream, W1, b1, newn, anp);
        hipLaunchKernelGGL(edge_mlp_mfma4, dim3(M / BROWS), dim3(256), 0, stream,
                           nodes, b2, W3, b3, w1f, w2f, anp, out);
    } else {
        hipLaunchKernelGGL(edge_mlp_f32, dim3(M / 32), dim3(256), 0, stream,
                           nodes, newn, W1, b1, W2, b2, W3, b3, out);
    }
}

// Round 6
// 96.737 us; speedup vs baseline: 3.3899x; 1.0105x over previous
//
#include <hip/hip_runtime.h>
#include <hip/hip_bf16.h>
#include <cstdint>
#include <cstddef>

#define BB 128
#define SS 4096
#define HH 128
#define N1 256
#define N2 64
#define BROWS 256   // rows per block = 4 waves * 64 rows; 256 | 4096 -> one b per block

typedef __bf16 bf16x8 __attribute__((ext_vector_type(8)));
typedef __bf16 bf16x4 __attribute__((ext_vector_type(4)));
typedef float  f32x4  __attribute__((ext_vector_type(4)));

// ---------------------------------------------------------------------------
// Prologue 1: weight frags (unchanged from round 5; layouts verified passing).
// w1f (nodes half, 64 KB): frag(g 0..15, ks 0..3):
//   val[l][j] = W1[32ks + 8*(l>>4) + j][16g + (l&15)]
// w2f (32 KB): A-frags of W2^T with the n-split k-slot relabel:
//   frag(mt2 0..3, ksp 0..7): val[l][j] = W2[c][16mt2 + (l&15)],
//   c = 32ksp + 16*(j>>2) + 4*(l>>4) + (j&3)
// ---------------------------------------------------------------------------
__global__ __launch_bounds__(256) void conv_weights(
    const float* __restrict__ W1, const float* __restrict__ W2,
    __bf16* __restrict__ w1f, __bf16* __restrict__ w2f)
{
    int tid = blockIdx.x * 256 + threadIdx.x;
    if (tid < 4096) {                        // W1 nodes half: 16 g * 4 ks * 64 lanes
        int lane = tid & 63, ks = (tid >> 6) & 3, g = tid >> 8;
        int col = 16 * g + (lane & 15);
        int kbase = 32 * ks + 8 * (lane >> 4);
        bf16x8 v;
#pragma unroll
        for (int j = 0; j < 8; ++j) v[j] = (__bf16)W1[(size_t)(kbase + j) * N1 + col];
        *(bf16x8*)(w1f + (size_t)tid * 8) = v;
    } else if (tid < 6144) {                 // W2: 4 mt2 * 8 ksp * 64 lanes
        int s = tid - 4096;
        int lane = s & 63, ksp = (s >> 6) & 7, mt2 = s >> 9;
        int q = lane >> 4, ln = lane & 15;
        bf16x8 v;
#pragma unroll
        for (int j = 0; j < 8; ++j) {
            int c = 32 * ksp + 16 * (j >> 2) + 4 * q + (j & 3);
            v[j] = (__bf16)W2[(size_t)c * N2 + 16 * mt2 + ln];
        }
        *(bf16x8*)(w2f + (size_t)s * 8) = v;
    }
}

// ---------------------------------------------------------------------------
// Prologue 2: an[b][c] = b1[c] + newn[b,:] . W1[128:256, c]
// ---------------------------------------------------------------------------
__global__ __launch_bounds__(256) void an_partial(
    const float* __restrict__ W1, const float* __restrict__ b1,
    const float* __restrict__ newn, __bf16* __restrict__ an)
{
    const int b = blockIdx.x, c = threadIdx.x;
    float acc = b1[c];
    const float* wp = W1 + (size_t)HH * N1 + c;   // rows 128..255, col c
    const float* nv = newn + (size_t)b * HH;
#pragma unroll 8
    for (int k = 0; k < HH; ++k)
        acc = fmaf(nv[k], wp[(size_t)k * N1], acc);
    an[(size_t)b * N1 + c] = (__bf16)acc;
}

// ---------------------------------------------------------------------------
// Main kernel, zero-LDS: 4 waves, wave w owns rows 64w..64w+63 (4 rowsets).
// X frags are loaded global->reg ONCE (they don't depend on ksp) and held
// resident (16 bf16x8 = 64 VGPRs). Weights stream from L2 per ksp, amortized
// over 64 rows/wave (2x round 5). No __shared__, no barriers, waves fully
// independent. Per ksp: 12 weight-frag loads + 48 register-fed MFMAs (~240cy)
// -> next-ksp loads pipeline under current MFMAs even at 2 waves/SIMD.
// ---------------------------------------------------------------------------
__global__ __launch_bounds__(256, 2) void edge_mlp_mfma5(
    const float* __restrict__ nodes,
    const float* __restrict__ b2,
    const float* __restrict__ W3, const float* __restrict__ b3,
    const __bf16* __restrict__ w1f, const __bf16* __restrict__ w2f,
    const __bf16* __restrict__ an,
    float* __restrict__ out)
{
    const int t = threadIdx.x;
    const int w = t >> 6, l = t & 63, q = l >> 4, ln = l & 15;
    const size_t row0 = (size_t)blockIdx.x * BROWS;
    const int b = (int)(row0 >> 12);

    // ---- X frags: [rs][ks], lane (q,ln) of rowset rs holds
    //      X[64w+16rs+ln][32ks+8q .. +8) as bf16x8 (B-frag of 16x16x32) ----
    bf16x8 xf[4][4];
#pragma unroll
    for (int rs = 0; rs < 4; ++rs) {
        const float* rp = nodes + (row0 + 64 * w + 16 * rs + ln) * HH + 8 * q;
#pragma unroll
        for (int ks = 0; ks < 4; ++ks) {
            float4 f0 = *(const float4*)(rp + 32 * ks);
            float4 f1 = *(const float4*)(rp + 32 * ks + 4);
            bf16x8 v;
            v[0] = (__bf16)f0.x; v[1] = (__bf16)f0.y; v[2] = (__bf16)f0.z; v[3] = (__bf16)f0.w;
            v[4] = (__bf16)f1.x; v[5] = (__bf16)f1.y; v[6] = (__bf16)f1.z; v[7] = (__bf16)f1.w;
            xf[rs][ks] = v;
        }
    }

    // ---- h2 accumulators [rs][mt2], bias-initialized ----
    f32x4 acc2[4][4];
#pragma unroll
    for (int mt2 = 0; mt2 < 4; ++mt2) {
        float4 bv = *(const float4*)(b2 + 16 * mt2 + 4 * q);
#pragma unroll
        for (int rs = 0; rs < 4; ++rs) {
            acc2[rs][mt2][0] = bv.x; acc2[rs][mt2][1] = bv.y;
            acc2[rs][mt2][2] = bv.z; acc2[rs][mt2][3] = bv.w;
        }
    }

    const __bf16* anb = an + (size_t)b * N1;

    // ---- main loop over g-pairs / layer-2 k-steps ----
#pragma unroll 1
    for (int ksp = 0; ksp < 8; ++ksp) {
        bf16x8 af0[4], af1[4], a2f[4];
#pragma unroll
        for (int ks = 0; ks < 4; ++ks) {
            af0[ks] = *(const bf16x8*)(w1f + ((size_t)((2 * ksp)     * 4 + ks) * 64 + l) * 8);
            af1[ks] = *(const bf16x8*)(w1f + ((size_t)((2 * ksp + 1) * 4 + ks) * 64 + l) * 8);
        }
#pragma unroll
        for (int mt2 = 0; mt2 < 4; ++mt2)
            a2f[mt2] = *(const bf16x8*)(w2f + ((size_t)(mt2 * 8 + ksp) * 64 + l) * 8);

        // newn+bias partial for this g-pair (broadcast 8B loads)
        f32x4 an0, an1;
        {
            bf16x4 a0 = *(const bf16x4*)(anb + 32 * ksp + 4 * q);
            bf16x4 a1 = *(const bf16x4*)(anb + 32 * ksp + 16 + 4 * q);
#pragma unroll
            for (int j = 0; j < 4; ++j) { an0[j] = (float)a0[j]; an1[j] = (float)a1[j]; }
        }

#pragma unroll
        for (int rs = 0; rs < 4; ++rs) {
            f32x4 alo = an0, ahi = an1;
#pragma unroll
            for (int ks = 0; ks < 4; ++ks) {
                alo = __builtin_amdgcn_mfma_f32_16x16x32_bf16(af0[ks], xf[rs][ks], alo, 0, 0, 0);
                ahi = __builtin_amdgcn_mfma_f32_16x16x32_bf16(af1[ks], xf[rs][ks], ahi, 0, 0, 0);
            }
            bf16x8 bfrag;
#pragma unroll
            for (int j = 0; j < 4; ++j) {
                bfrag[j]     = (__bf16)fmaxf(alo[j], 0.0f);
                bfrag[4 + j] = (__bf16)fmaxf(ahi[j], 0.0f);
            }
#pragma unroll
            for (int mt2 = 0; mt2 < 4; ++mt2)
                acc2[rs][mt2] = __builtin_amdgcn_mfma_f32_16x16x32_bf16(a2f[mt2], bfrag, acc2[rs][mt2], 0, 0, 0);
        }
    }

    // ---- layer 3: relu(h2).W3 + b3, reduce over q-groups, sigmoid ----
    const float b3v = b3[0];
    float4 w3v[4];
#pragma unroll
    for (int mt2 = 0; mt2 < 4; ++mt2) w3v[mt2] = *(const float4*)(W3 + 16 * mt2 + 4 * q);
#pragma unroll
    for (int rs = 0; rs < 4; ++rs) {
        float sum = 0.f;
#pragma unroll
        for (int mt2 = 0; mt2 < 4; ++mt2) {
            sum += fmaxf(acc2[rs][mt2][0], 0.f) * w3v[mt2].x
                 + fmaxf(acc2[rs][mt2][1], 0.f) * w3v[mt2].y
                 + fmaxf(acc2[rs][mt2][2], 0.f) * w3v[mt2].z
                 + fmaxf(acc2[rs][mt2][3], 0.f) * w3v[mt2].w;
        }
        sum += __shfl_xor(sum, 16, 64);
        sum += __shfl_xor(sum, 32, 64);
        if (q == 0) {
            float v = sum + b3v;
            out[row0 + 64 * w + 16 * rs + ln] = 1.0f / (1.0f + __expf(-v));
        }
    }
}

// ---------------------------------------------------------------------------
// fp32 fallback if workspace is too small
// ---------------------------------------------------------------------------
__global__ __launch_bounds__(256, 4) void edge_mlp_f32(
    const float* __restrict__ nodes, const float* __restrict__ newn,
    const float* __restrict__ W1, const float* __restrict__ b1,
    const float* __restrict__ W2, const float* __restrict__ b2,
    const float* __restrict__ W3, const float* __restrict__ b3,
    float* __restrict__ out)
{
    __shared__ float buf[32][256];
    const int t = threadIdx.x;
    const long r0 = (long)blockIdx.x * 32;
    const int b = (int)(r0 >> 12);
    const float4* src = (const float4*)(nodes + (size_t)r0 * HH);
#pragma unroll
    for (int i = 0; i < 4; ++i) {
        int idx = t + i * 256;
        *(float4*)&buf[idx >> 5][(idx & 31) * 4] = src[idx];
    }
    {
        float nv = newn[b * HH + (t & 127)];
        for (int r = (t >> 7); r < 32; r += 2) buf[r][HH + (t & 127)] = nv;
    }
    __syncthreads();
    const int c0 = t & 63, rb = (t >> 6) * 8;
    float acc[8][4];
#pragma unroll
    for (int ci = 0; ci < 4; ++ci) {
        float bv = b1[c0 + 64 * ci];
#pragma unroll
        for (int r = 0; r < 8; ++r) acc[r][ci] = bv;
    }
    for (int k = 0; k < 256; k += 4) {
        float wv[4][4];
#pragma unroll
        for (int kk = 0; kk < 4; ++kk)
#pragma unroll
            for (int ci = 0; ci < 4; ++ci) wv[kk][ci] = W1[(k + kk) * N1 + c0 + 64 * ci];
#pragma unroll
        for (int r = 0; r < 8; ++r) {
            float4 x = *(const float4*)&buf[rb + r][k];
#pragma unroll
            for (int ci = 0; ci < 4; ++ci) {
                acc[r][ci] = fmaf(x.x, wv[0][ci], acc[r][ci]);
                acc[r][ci] = fmaf(x.y, wv[1][ci], acc[r][ci]);
                acc[r][ci] = fmaf(x.z, wv[2][ci], acc[r][ci]);
                acc[r][ci] = fmaf(x.w, wv[3][ci], acc[r][ci]);
            }
        }
    }
    __syncthreads();
#pragma unroll
    for (int r = 0; r < 8; ++r)
#pragma unroll
        for (int ci = 0; ci < 4; ++ci) buf[rb + r][c0 + 64 * ci] = fmaxf(acc[r][ci], 0.0f);
    __syncthreads();
    const int c2 = t & 31, g2 = t >> 5;
    float acc2[4][2];
#pragma unroll
    for (int cj = 0; cj < 2; ++cj) {
        float bv = b2[c2 + 32 * cj];
#pragma unroll
        for (int rr = 0; rr < 4; ++rr) acc2[rr][cj] = bv;
    }
    for (int k = 0; k < 256; k += 4) {
        float w2v[4][2];
#pragma unroll
        for (int kk = 0; kk < 4; ++kk)
#pragma unroll
            for (int cj = 0; cj < 2; ++cj) w2v[kk][cj] = W2[(k + kk) * N2 + c2 + 32 * cj];
#pragma unroll
        for (int rr = 0; rr < 4; ++rr) {
            float4 x = *(const float4*)&buf[4 * g2 + rr][k];
#pragma unroll
            for (int cj = 0; cj < 2; ++cj) {
                acc2[rr][cj] = fmaf(x.x, w2v[0][cj], acc2[rr][cj]);
                acc2[rr][cj] = fmaf(x.y, w2v[1][cj], acc2[rr][cj]);
                acc2[rr][cj] = fmaf(x.z, w2v[2][cj], acc2[rr][cj]);
                acc2[rr][cj] = fmaf(x.w, w2v[3][cj], acc2[rr][cj]);
            }
        }
    }
    const float w3a = W3[c2], w3b = W3[c2 + 32], b3v = b3[0];
    float p[4];
#pragma unroll
    for (int rr = 0; rr < 4; ++rr)
        p[rr] = fmaf(fmaxf(acc2[rr][0], 0.f), w3a, fmaxf(acc2[rr][1], 0.f) * w3b);
#pragma unroll
    for (int off = 16; off >= 1; off >>= 1)
#pragma unroll
        for (int rr = 0; rr < 4; ++rr) p[rr] += __shfl_xor(p[rr], off, 64);
    if (c2 == 0)
#pragma unroll
        for (int rr = 0; rr < 4; ++rr)
            out[r0 + 4 * g2 + rr] = 1.0f / (1.0f + __expf(-(p[rr] + b3v)));
}

extern "C" void kernel_launch(void* const* d_in, const int* in_sizes, int n_in,
                              void* d_out, int out_size, void* d_ws, size_t ws_size,
                              hipStream_t stream) {
    const float* nodes = (const float*)d_in[0];
    const float* newn  = (const float*)d_in[1];
    const float* W1    = (const float*)d_in[2];
    const float* b1    = (const float*)d_in[3];
    const float* W2    = (const float*)d_in[4];
    const float* b2    = (const float*)d_in[5];
    const float* W3    = (const float*)d_in[6];
    const float* b3    = (const float*)d_in[7];
    float* out = (float*)d_out;
    const int M = BB * SS;

    if (ws_size >= 163840) {               // 64K w1f + 32K w2f + 64K an
        __bf16* w1f = (__bf16*)d_ws;                   // 32768 elems
        __bf16* w2f = (__bf16*)d_ws + 32768;           // 16384 elems
        __bf16* anp = (__bf16*)d_ws + 49152;           // 32768 elems
        hipLaunchKernelGGL(conv_weights, dim3(24), dim3(256), 0, stream, W1, W2, w1f, w2f);
        hipLaunchKernelGGL(an_partial, dim3(BB), dim3(256), 0, stream, W1, b1, newn, anp);
        hipLaunchKernelGGL(edge_mlp_mfma5, dim3(M / BROWS), dim3(256), 0, stream,
                           nodes, b2, W3, b3, w1f, w2f, anp, out);
    } else {
        hipLaunchKernelGGL(edge_mlp_f32, dim3(M / 32), dim3(256), 0, stream,
                           nodes, newn, W1, b1, W2, b2, W3, b3, out);
    }
}

// Round 7
// 93.132 us; speedup vs baseline: 3.5211x; 1.0387x over previous
//
#include <hip/hip_runtime.h>
#include <hip/hip_bf16.h>
#include <cstdint>
#include <cstddef>

#define BB 128
#define SS 4096
#define HH 128
#define N1 256
#define N2 64
#define BROWS 512   // rows per block = 16 waves * 32 rows; 512 | 4096 -> one b per block

typedef __bf16 bf16x8 __attribute__((ext_vector_type(8)));
typedef __bf16 bf16x4 __attribute__((ext_vector_type(4)));
typedef float  f32x4  __attribute__((ext_vector_type(4)));

// ---------------------------------------------------------------------------
// Merged prologue. Blocks 0..23: weight frags (layouts verified rounds 4-6).
// Blocks 24..151: an[b][c] = b1[c] + newn[b,:] . W1[128:256, c].
// w1f (nodes half, 64 KB): frag(g 0..15, ks 0..3):
//   val[l][j] = W1[32ks + 8*(l>>4) + j][16g + (l&15)]
// w2f (32 KB, contiguous after w1f): A-frags of W2^T, n-split k-slot relabel:
//   frag(mt2 0..3, ksp 0..7): val[l][j] = W2[c][16mt2 + (l&15)],
//   c = 32ksp + 16*(j>>2) + 4*(l>>4) + (j&3)
// ---------------------------------------------------------------------------
__global__ __launch_bounds__(256) void prologue(
    const float* __restrict__ W1, const float* __restrict__ W2,
    const float* __restrict__ b1, const float* __restrict__ newn,
    __bf16* __restrict__ w1f, __bf16* __restrict__ w2f, __bf16* __restrict__ an)
{
    const int blk = blockIdx.x;
    if (blk < 24) {
        int tid = blk * 256 + threadIdx.x;
        if (tid < 4096) {                        // W1 nodes half: 16 g * 4 ks * 64 lanes
            int lane = tid & 63, ks = (tid >> 6) & 3, g = tid >> 8;
            int col = 16 * g + (lane & 15);
            int kbase = 32 * ks + 8 * (lane >> 4);
            bf16x8 v;
#pragma unroll
            for (int j = 0; j < 8; ++j) v[j] = (__bf16)W1[(size_t)(kbase + j) * N1 + col];
            *(bf16x8*)(w1f + (size_t)tid * 8) = v;
        } else {                                 // W2: 4 mt2 * 8 ksp * 64 lanes
            int s = tid - 4096;
            int lane = s & 63, ksp = (s >> 6) & 7, mt2 = s >> 9;
            int q = lane >> 4, ln = lane & 15;
            bf16x8 v;
#pragma unroll
            for (int j = 0; j < 8; ++j) {
                int c = 32 * ksp + 16 * (j >> 2) + 4 * q + (j & 3);
                v[j] = (__bf16)W2[(size_t)c * N2 + 16 * mt2 + ln];
            }
            *(bf16x8*)(w2f + (size_t)s * 8) = v;
        }
    } else {
        const int b = blk - 24, c = threadIdx.x;
        float acc = b1[c];
        const float* wp = W1 + (size_t)HH * N1 + c;   // rows 128..255, col c
        const float* nv = newn + (size_t)b * HH;
#pragma unroll 8
        for (int k = 0; k < HH; ++k)
            acc = fmaf(nv[k], wp[(size_t)k * N1], acc);
        an[(size_t)b * N1 + c] = (__bf16)acc;
    }
}

// ---------------------------------------------------------------------------
// Main kernel. 1024 threads = 16 waves; wave w owns rows 32w..32w+31 (2 row-
// sets of 16). The full 96 KB weight-frag set is staged into LDS once per
// block (flat uint4 copy; w1f/w2f contiguous in ws) and every wave reads its
// frags via ds_read_b128 (lane l -> bytes l*16 of a 1 KB frag: conflict-free,
// LDS pipe, off the VMEM/L1 path). X held in registers (loaded once, global).
// Per ksp: 12 LDS frag reads + an broadcast + 2 rowsets x (8 L1 MFMAs ->
// register relu/cvt relabel -> 4 L2 MFMAs). One barrier per block.
// launch_bounds(1024,4): VGPR<=128 so the 16-wave block is schedulable;
// 16 waves/CU = 4 waves/SIMD.
// ---------------------------------------------------------------------------
__global__ __launch_bounds__(1024, 4) void edge_mlp_mfma6(
    const float* __restrict__ nodes,
    const float* __restrict__ b2,
    const float* __restrict__ W3, const float* __restrict__ b3,
    const __bf16* __restrict__ wsrc,   // w1f||w2f, 98304 B contiguous
    const __bf16* __restrict__ an,
    float* __restrict__ out)
{
    __shared__ __bf16 wsm[49152];      // 96 KB: w1s (32768 elems) + w2s (16384)

    const int t = threadIdx.x;
    const int w = t >> 6, l = t & 63, q = l >> 4, ln = l & 15;
    const size_t row0 = (size_t)blockIdx.x * BROWS;
    const int b = (int)(row0 >> 12);

    // ---- stage weight frags: 6144 uint4 = 96 KB, coalesced flat copy ----
#pragma unroll
    for (int i = 0; i < 6; ++i) {
        int idx = i * 1024 + t;
        ((uint4*)wsm)[idx] = ((const uint4*)wsrc)[idx];
    }

    // ---- X frags (global->reg, overlaps the LDS staging): [rs][ks] ----
    bf16x8 xf[2][4];
#pragma unroll
    for (int rs = 0; rs < 2; ++rs) {
        const float* rp = nodes + (row0 + 32 * w + 16 * rs + ln) * HH + 8 * q;
#pragma unroll
        for (int ks = 0; ks < 4; ++ks) {
            float4 f0 = *(const float4*)(rp + 32 * ks);
            float4 f1 = *(const float4*)(rp + 32 * ks + 4);
            bf16x8 v;
            v[0] = (__bf16)f0.x; v[1] = (__bf16)f0.y; v[2] = (__bf16)f0.z; v[3] = (__bf16)f0.w;
            v[4] = (__bf16)f1.x; v[5] = (__bf16)f1.y; v[6] = (__bf16)f1.z; v[7] = (__bf16)f1.w;
            xf[rs][ks] = v;
        }
    }

    // ---- h2 accumulators [rs][mt2], bias-initialized ----
    f32x4 acc2[2][4];
#pragma unroll
    for (int mt2 = 0; mt2 < 4; ++mt2) {
        float4 bv = *(const float4*)(b2 + 16 * mt2 + 4 * q);
#pragma unroll
        for (int rs = 0; rs < 2; ++rs) {
            acc2[rs][mt2][0] = bv.x; acc2[rs][mt2][1] = bv.y;
            acc2[rs][mt2][2] = bv.z; acc2[rs][mt2][3] = bv.w;
        }
    }

    const __bf16* anb = an + (size_t)b * N1;
    const __bf16* w1s = wsm;            // 16 g * 4 ks frags
    const __bf16* w2s = wsm + 32768;    // 4 mt2 * 8 ksp frags

    __syncthreads();   // weight frags visible

    // ---- main loop over g-pairs / layer-2 k-steps ----
#pragma unroll 1
    for (int ksp = 0; ksp < 8; ++ksp) {
        bf16x8 af0[4], af1[4], a2f[4];
#pragma unroll
        for (int ks = 0; ks < 4; ++ks) {
            af0[ks] = *(const bf16x8*)(w1s + ((size_t)((2 * ksp)     * 4 + ks) * 64 + l) * 8);
            af1[ks] = *(const bf16x8*)(w1s + ((size_t)((2 * ksp + 1) * 4 + ks) * 64 + l) * 8);
        }
#pragma unroll
        for (int mt2 = 0; mt2 < 4; ++mt2)
            a2f[mt2] = *(const bf16x8*)(w2s + ((size_t)(mt2 * 8 + ksp) * 64 + l) * 8);

        // newn+bias partial for this g-pair (broadcast 8B loads, L1-hot)
        f32x4 an0, an1;
        {
            bf16x4 a0 = *(const bf16x4*)(anb + 32 * ksp + 4 * q);
            bf16x4 a1 = *(const bf16x4*)(anb + 32 * ksp + 16 + 4 * q);
#pragma unroll
            for (int j = 0; j < 4; ++j) { an0[j] = (float)a0[j]; an1[j] = (float)a1[j]; }
        }

#pragma unroll
        for (int rs = 0; rs < 2; ++rs) {
            f32x4 alo = an0, ahi = an1;
#pragma unroll
            for (int ks = 0; ks < 4; ++ks) {
                alo = __builtin_amdgcn_mfma_f32_16x16x32_bf16(af0[ks], xf[rs][ks], alo, 0, 0, 0);
                ahi = __builtin_amdgcn_mfma_f32_16x16x32_bf16(af1[ks], xf[rs][ks], ahi, 0, 0, 0);
            }
            bf16x8 bfrag;
#pragma unroll
            for (int j = 0; j < 4; ++j) {
                bfrag[j]     = (__bf16)fmaxf(alo[j], 0.0f);
                bfrag[4 + j] = (__bf16)fmaxf(ahi[j], 0.0f);
            }
#pragma unroll
            for (int mt2 = 0; mt2 < 4; ++mt2)
                acc2[rs][mt2] = __builtin_amdgcn_mfma_f32_16x16x32_bf16(a2f[mt2], bfrag, acc2[rs][mt2], 0, 0, 0);
        }
    }

    // ---- layer 3: relu(h2).W3 + b3, reduce over q-groups, sigmoid ----
    const float b3v = b3[0];
#pragma unroll
    for (int rs = 0; rs < 2; ++rs) {
        float sum = 0.f;
#pragma unroll
        for (int mt2 = 0; mt2 < 4; ++mt2) {
            float4 w3v = *(const float4*)(W3 + 16 * mt2 + 4 * q);
            sum += fmaxf(acc2[rs][mt2][0], 0.f) * w3v.x
                 + fmaxf(acc2[rs][mt2][1], 0.f) * w3v.y
                 + fmaxf(acc2[rs][mt2][2], 0.f) * w3v.z
                 + fmaxf(acc2[rs][mt2][3], 0.f) * w3v.w;
        }
        sum += __shfl_xor(sum, 16, 64);
        sum += __shfl_xor(sum, 32, 64);
        if (q == 0) {
            float v = sum + b3v;
            out[row0 + 32 * w + 16 * rs + ln] = 1.0f / (1.0f + __expf(-v));
        }
    }
}

// ---------------------------------------------------------------------------
// fp32 fallback if workspace is too small
// ---------------------------------------------------------------------------
__global__ __launch_bounds__(256, 4) void edge_mlp_f32(
    const float* __restrict__ nodes, const float* __restrict__ newn,
    const float* __restrict__ W1, const float* __restrict__ b1,
    const float* __restrict__ W2, const float* __restrict__ b2,
    const float* __restrict__ W3, const float* __restrict__ b3,
    float* __restrict__ out)
{
    __shared__ float buf[32][256];
    const int t = threadIdx.x;
    const long r0 = (long)blockIdx.x * 32;
    const int b = (int)(r0 >> 12);
    const float4* src = (const float4*)(nodes + (size_t)r0 * HH);
#pragma unroll
    for (int i = 0; i < 4; ++i) {
        int idx = t + i * 256;
        *(float4*)&buf[idx >> 5][(idx & 31) * 4] = src[idx];
    }
    {
        float nv = newn[b * HH + (t & 127)];
        for (int r = (t >> 7); r < 32; r += 2) buf[r][HH + (t & 127)] = nv;
    }
    __syncthreads();
    const int c0 = t & 63, rb = (t >> 6) * 8;
    float acc[8][4];
#pragma unroll
    for (int ci = 0; ci < 4; ++ci) {
        float bv = b1[c0 + 64 * ci];
#pragma unroll
        for (int r = 0; r < 8; ++r) acc[r][ci] = bv;
    }
    for (int k = 0; k < 256; k += 4) {
        float wv[4][4];
#pragma unroll
        for (int kk = 0; kk < 4; ++kk)
#pragma unroll
            for (int ci = 0; ci < 4; ++ci) wv[kk][ci] = W1[(k + kk) * N1 + c0 + 64 * ci];
#pragma unroll
        for (int r = 0; r < 8; ++r) {
            float4 x = *(const float4*)&buf[rb + r][k];
#pragma unroll
            for (int ci = 0; ci < 4; ++ci) {
                acc[r][ci] = fmaf(x.x, wv[0][ci], acc[r][ci]);
                acc[r][ci] = fmaf(x.y, wv[1][ci], acc[r][ci]);
                acc[r][ci] = fmaf(x.z, wv[2][ci], acc[r][ci]);
                acc[r][ci] = fmaf(x.w, wv[3][ci], acc[r][ci]);
            }
        }
    }
    __syncthreads();
#pragma unroll
    for (int r = 0; r < 8; ++r)
#pragma unroll
        for (int ci = 0; ci < 4; ++ci) buf[rb + r][c0 + 64 * ci] = fmaxf(acc[r][ci], 0.0f);
    __syncthreads();
    const int c2 = t & 31, g2 = t >> 5;
    float acc2[4][2];
#pragma unroll
    for (int cj = 0; cj < 2; ++cj) {
        float bv = b2[c2 + 32 * cj];
#pragma unroll
        for (int rr = 0; rr < 4; ++rr) acc2[rr][cj] = bv;
    }
    for (int k = 0; k < 256; k += 4) {
        float w2v[4][2];
#pragma unroll
        for (int kk = 0; kk < 4; ++kk)
#pragma unroll
            for (int cj = 0; cj < 2; ++cj) w2v[kk][cj] = W2[(k + kk) * N2 + c2 + 32 * cj];
#pragma unroll
        for (int rr = 0; rr < 4; ++rr) {
            float4 x = *(const float4*)&buf[4 * g2 + rr][k];
#pragma unroll
            for (int cj = 0; cj < 2; ++cj) {
                acc2[rr][cj] = fmaf(x.x, w2v[0][cj], acc2[rr][cj]);
                acc2[rr][cj] = fmaf(x.y, w2v[1][cj], acc2[rr][cj]);
                acc2[rr][cj] = fmaf(x.z, w2v[2][cj], acc2[rr][cj]);
                acc2[rr][cj] = fmaf(x.w, w2v[3][cj], acc2[rr][cj]);
            }
        }
    }
    const float w3a = W3[c2], w3b = W3[c2 + 32], b3v = b3[0];
    float p[4];
#pragma unroll
    for (int rr = 0; rr < 4; ++rr)
        p[rr] = fmaf(fmaxf(acc2[rr][0], 0.f), w3a, fmaxf(acc2[rr][1], 0.f) * w3b);
#pragma unroll
    for (int off = 16; off >= 1; off >>= 1)
#pragma unroll
        for (int rr = 0; rr < 4; ++rr) p[rr] += __shfl_xor(p[rr], off, 64);
    if (c2 == 0)
#pragma unroll
        for (int rr = 0; rr < 4; ++rr)
            out[r0 + 4 * g2 + rr] = 1.0f / (1.0f + __expf(-(p[rr] + b3v)));
}

extern "C" void kernel_launch(void* const* d_in, const int* in_sizes, int n_in,
                              void* d_out, int out_size, void* d_ws, size_t ws_size,
                              hipStream_t stream) {
    const float* nodes = (const float*)d_in[0];
    const float* newn  = (const float*)d_in[1];
    const float* W1    = (const float*)d_in[2];
    const float* b1    = (const float*)d_in[3];
    const float* W2    = (const float*)d_in[4];
    const float* b2    = (const float*)d_in[5];
    const float* W3    = (const float*)d_in[6];
    const float* b3    = (const float*)d_in[7];
    float* out = (float*)d_out;
    const int M = BB * SS;

    if (ws_size >= 163840) {               // 64K w1f + 32K w2f + 64K an
        __bf16* w1f = (__bf16*)d_ws;                   // 32768 elems (w2f contiguous after)
        __bf16* w2f = (__bf16*)d_ws + 32768;           // 16384 elems
        __bf16* anp = (__bf16*)d_ws + 49152;           // 32768 elems
        hipLaunchKernelGGL(prologue, dim3(24 + BB), dim3(256), 0, stream,
                           W1, W2, b1, newn, w1f, w2f, anp);
        hipLaunchKernelGGL(edge_mlp_mfma6, dim3(M / BROWS), dim3(1024), 0, stream,
                           nodes, b2, W3, b3, w1f, anp, out);
    } else {
        hipLaunchKernelGGL(edge_mlp_f32, dim3(M / 32), dim3(256), 0, stream,
                           nodes, newn, W1, b1, W2, b2, W3, b3, out);
    }
}

// Round 8
// 83.660 us; speedup vs baseline: 3.9198x; 1.1132x over previous
//
#include <hip/hip_runtime.h>
#include <hip/hip_bf16.h>
#include <cstdint>
#include <cstddef>

#define BB 128
#define SS 4096
#define HH 128
#define N1 256
#define N2 64
#define BROWS 256   // rows per block = 8 waves * 32 rows; 256 | 4096 -> one b per block

typedef __bf16 bf16x8 __attribute__((ext_vector_type(8)));
typedef __bf16 bf16x4 __attribute__((ext_vector_type(4)));
typedef float  f32x4  __attribute__((ext_vector_type(4)));

// ---------------------------------------------------------------------------
// Merged prologue (layouts verified rounds 4-7).
// Blocks 0..23: weight frags. Blocks 24..151: an partial.
// w1f (nodes half, 64 KB): frag(g 0..15, ks 0..3):
//   val[l][j] = W1[32ks + 8*(l>>4) + j][16g + (l&15)]
// w2f (32 KB): A-frags of W2^T, n-split k-slot relabel:
//   frag(mt2 0..3, ksp 0..7): val[l][j] = W2[c][16mt2 + (l&15)],
//   c = 32ksp + 16*(j>>2) + 4*(l>>4) + (j&3)
// an[b][c] = b1[c] + newn[b,:] . W1[128:256, c]
// ---------------------------------------------------------------------------
__global__ __launch_bounds__(256) void prologue(
    const float* __restrict__ W1, const float* __restrict__ W2,
    const float* __restrict__ b1, const float* __restrict__ newn,
    __bf16* __restrict__ w1f, __bf16* __restrict__ w2f, __bf16* __restrict__ an)
{
    const int blk = blockIdx.x;
    if (blk < 24) {
        int tid = blk * 256 + threadIdx.x;
        if (tid < 4096) {                        // W1 nodes half: 16 g * 4 ks * 64 lanes
            int lane = tid & 63, ks = (tid >> 6) & 3, g = tid >> 8;
            int col = 16 * g + (lane & 15);
            int kbase = 32 * ks + 8 * (lane >> 4);
            bf16x8 v;
#pragma unroll
            for (int j = 0; j < 8; ++j) v[j] = (__bf16)W1[(size_t)(kbase + j) * N1 + col];
            *(bf16x8*)(w1f + (size_t)tid * 8) = v;
        } else {                                 // W2: 4 mt2 * 8 ksp * 64 lanes
            int s = tid - 4096;
            int lane = s & 63, ksp = (s >> 6) & 7, mt2 = s >> 9;
            int q = lane >> 4, ln = lane & 15;
            bf16x8 v;
#pragma unroll
            for (int j = 0; j < 8; ++j) {
                int c = 32 * ksp + 16 * (j >> 2) + 4 * q + (j & 3);
                v[j] = (__bf16)W2[(size_t)c * N2 + 16 * mt2 + ln];
            }
            *(bf16x8*)(w2f + (size_t)s * 8) = v;
        }
    } else {
        const int b = blk - 24, c = threadIdx.x;
        float acc = b1[c];
        const float* wp = W1 + (size_t)HH * N1 + c;   // rows 128..255, col c
        const float* nv = newn + (size_t)b * HH;
#pragma unroll 8
        for (int k = 0; k < HH; ++k)
            acc = fmaf(nv[k], wp[(size_t)k * N1], acc);
        an[(size_t)b * N1 + c] = (__bf16)acc;
    }
}

// ---------------------------------------------------------------------------
// Main kernel. 512 threads = 8 waves; wave w owns rows 32w..32w+31 (2 rowsets
// of 16). Only the 64 KB w1 frag set is staged in LDS (flat uint4 copy) ->
// LDS/block = 64 KB -> 2 blocks/CU resident: block N+1's X-load burst
// overlaps block N's compute phase (this was the round-7 wall: 96 KB LDS ->
// 1 block/CU -> serial load/compute phases). w2 frags (32 KB, L2-hot,
// identical for every block) stream via VMEM per ksp. X in registers.
// Per ksp: 8 LDS frag reads + 4 VMEM w2 reads + an broadcast + 2 rowsets x
// (8 L1 MFMAs -> register relu/cvt relabel -> 4 L2 MFMAs). One barrier.
// launch_bounds(512,4): VGPR<=128, 4 waves/SIMD from the 2 resident blocks.
// ---------------------------------------------------------------------------
__global__ __launch_bounds__(512, 4) void edge_mlp_mfma7(
    const float* __restrict__ nodes,
    const float* __restrict__ b2,
    const float* __restrict__ W3, const float* __restrict__ b3,
    const __bf16* __restrict__ w1f,    // 32768 elems in ws
    const __bf16* __restrict__ w2f,    // 16384 elems in ws
    const __bf16* __restrict__ an,
    float* __restrict__ out)
{
    __shared__ __bf16 w1s[32768];      // 64 KB

    const int t = threadIdx.x;
    const int w = t >> 6, l = t & 63, q = l >> 4, ln = l & 15;
    const size_t row0 = (size_t)blockIdx.x * BROWS;
    const int b = (int)(row0 >> 12);

    // ---- X frags (global->reg): [rs][ks]; lane (q,ln) of rowset rs holds
    //      X[32w+16rs+ln][32ks+8q .. +8) as the MFMA B-frag ----
    bf16x8 xf[2][4];
#pragma unroll
    for (int rs = 0; rs < 2; ++rs) {
        const float* rp = nodes + (row0 + 32 * w + 16 * rs + ln) * HH + 8 * q;
#pragma unroll
        for (int ks = 0; ks < 4; ++ks) {
            float4 f0 = *(const float4*)(rp + 32 * ks);
            float4 f1 = *(const float4*)(rp + 32 * ks + 4);
            bf16x8 v;
            v[0] = (__bf16)f0.x; v[1] = (__bf16)f0.y; v[2] = (__bf16)f0.z; v[3] = (__bf16)f0.w;
            v[4] = (__bf16)f1.x; v[5] = (__bf16)f1.y; v[6] = (__bf16)f1.z; v[7] = (__bf16)f1.w;
            xf[rs][ks] = v;
        }
    }

    // ---- stage w1 frags: 4096 uint4 = 64 KB, coalesced flat copy ----
#pragma unroll
    for (int i = 0; i < 8; ++i) {
        int idx = i * 512 + t;
        ((uint4*)w1s)[idx] = ((const uint4*)w1f)[idx];
    }

    // ---- h2 accumulators [rs][mt2], bias-initialized ----
    f32x4 acc2[2][4];
#pragma unroll
    for (int mt2 = 0; mt2 < 4; ++mt2) {
        float4 bv = *(const float4*)(b2 + 16 * mt2 + 4 * q);
#pragma unroll
        for (int rs = 0; rs < 2; ++rs) {
            acc2[rs][mt2][0] = bv.x; acc2[rs][mt2][1] = bv.y;
            acc2[rs][mt2][2] = bv.z; acc2[rs][mt2][3] = bv.w;
        }
    }

    const __bf16* anb = an + (size_t)b * N1;

    __syncthreads();   // w1 frags visible

    // ---- main loop over g-pairs / layer-2 k-steps ----
#pragma unroll 1
    for (int ksp = 0; ksp < 8; ++ksp) {
        bf16x8 af0[4], af1[4], a2f[4];
#pragma unroll
        for (int ks = 0; ks < 4; ++ks) {
            af0[ks] = *(const bf16x8*)(w1s + ((size_t)((2 * ksp)     * 4 + ks) * 64 + l) * 8);
            af1[ks] = *(const bf16x8*)(w1s + ((size_t)((2 * ksp + 1) * 4 + ks) * 64 + l) * 8);
        }
#pragma unroll
        for (int mt2 = 0; mt2 < 4; ++mt2)
            a2f[mt2] = *(const bf16x8*)(w2f + ((size_t)(mt2 * 8 + ksp) * 64 + l) * 8);

        // newn+bias partial for this g-pair (broadcast 8B loads, L1-hot)
        f32x4 an0, an1;
        {
            bf16x4 a0 = *(const bf16x4*)(anb + 32 * ksp + 4 * q);
            bf16x4 a1 = *(const bf16x4*)(anb + 32 * ksp + 16 + 4 * q);
#pragma unroll
            for (int j = 0; j < 4; ++j) { an0[j] = (float)a0[j]; an1[j] = (float)a1[j]; }
        }

#pragma unroll
        for (int rs = 0; rs < 2; ++rs) {
            f32x4 alo = an0, ahi = an1;
#pragma unroll
            for (int ks = 0; ks < 4; ++ks) {
                alo = __builtin_amdgcn_mfma_f32_16x16x32_bf16(af0[ks], xf[rs][ks], alo, 0, 0, 0);
                ahi = __builtin_amdgcn_mfma_f32_16x16x32_bf16(af1[ks], xf[rs][ks], ahi, 0, 0, 0);
            }
            bf16x8 bfrag;
#pragma unroll
            for (int j = 0; j < 4; ++j) {
                bfrag[j]     = (__bf16)fmaxf(alo[j], 0.0f);
                bfrag[4 + j] = (__bf16)fmaxf(ahi[j], 0.0f);
            }
#pragma unroll
            for (int mt2 = 0; mt2 < 4; ++mt2)
                acc2[rs][mt2] = __builtin_amdgcn_mfma_f32_16x16x32_bf16(a2f[mt2], bfrag, acc2[rs][mt2], 0, 0, 0);
        }
    }

    // ---- layer 3: relu(h2).W3 + b3, reduce over q-groups, sigmoid ----
    const float b3v = b3[0];
#pragma unroll
    for (int rs = 0; rs < 2; ++rs) {
        float sum = 0.f;
#pragma unroll
        for (int mt2 = 0; mt2 < 4; ++mt2) {
            float4 w3v = *(const float4*)(W3 + 16 * mt2 + 4 * q);
            sum += fmaxf(acc2[rs][mt2][0], 0.f) * w3v.x
                 + fmaxf(acc2[rs][mt2][1], 0.f) * w3v.y
                 + fmaxf(acc2[rs][mt2][2], 0.f) * w3v.z
                 + fmaxf(acc2[rs][mt2][3], 0.f) * w3v.w;
        }
        sum += __shfl_xor(sum, 16, 64);
        sum += __shfl_xor(sum, 32, 64);
        if (q == 0) {
            float v = sum + b3v;
            out[row0 + 32 * w + 16 * rs + ln] = 1.0f / (1.0f + __expf(-v));
        }
    }
}

// ---------------------------------------------------------------------------
// fp32 fallback if workspace is too small
// ---------------------------------------------------------------------------
__global__ __launch_bounds__(256, 4) void edge_mlp_f32(
    const float* __restrict__ nodes, const float* __restrict__ newn,
    const float* __restrict__ W1, const float* __restrict__ b1,
    const float* __restrict__ W2, const float* __restrict__ b2,
    const float* __restrict__ W3, const float* __restrict__ b3,
    float* __restrict__ out)
{
    __shared__ float buf[32][256];
    const int t = threadIdx.x;
    const long r0 = (long)blockIdx.x * 32;
    const int b = (int)(r0 >> 12);
    const float4* src = (const float4*)(nodes + (size_t)r0 * HH);
#pragma unroll
    for (int i = 0; i < 4; ++i) {
        int idx = t + i * 256;
        *(float4*)&buf[idx >> 5][(idx & 31) * 4] = src[idx];
    }
    {
        float nv = newn[b * HH + (t & 127)];
        for (int r = (t >> 7); r < 32; r += 2) buf[r][HH + (t & 127)] = nv;
    }
    __syncthreads();
    const int c0 = t & 63, rb = (t >> 6) * 8;
    float acc[8][4];
#pragma unroll
    for (int ci = 0; ci < 4; ++ci) {
        float bv = b1[c0 + 64 * ci];
#pragma unroll
        for (int r = 0; r < 8; ++r) acc[r][ci] = bv;
    }
    for (int k = 0; k < 256; k += 4) {
        float wv[4][4];
#pragma unroll
        for (int kk = 0; kk < 4; ++kk)
#pragma unroll
            for (int ci = 0; ci < 4; ++ci) wv[kk][ci] = W1[(k + kk) * N1 + c0 + 64 * ci];
#pragma unroll
        for (int r = 0; r < 8; ++r) {
            float4 x = *(const float4*)&buf[rb + r][k];
#pragma unroll
            for (int ci = 0; ci < 4; ++ci) {
                acc[r][ci] = fmaf(x.x, wv[0][ci], acc[r][ci]);
                acc[r][ci] = fmaf(x.y, wv[1][ci], acc[r][ci]);
                acc[r][ci] = fmaf(x.z, wv[2][ci], acc[r][ci]);
                acc[r][ci] = fmaf(x.w, wv[3][ci], acc[r][ci]);
            }
        }
    }
    __syncthreads();
#pragma unroll
    for (int r = 0; r < 8; ++r)
#pragma unroll
        for (int ci = 0; ci < 4; ++ci) buf[rb + r][c0 + 64 * ci] = fmaxf(acc[r][ci], 0.0f);
    __syncthreads();
    const int c2 = t & 31, g2 = t >> 5;
    float acc2[4][2];
#pragma unroll
    for (int cj = 0; cj < 2; ++cj) {
        float bv = b2[c2 + 32 * cj];
#pragma unroll
        for (int rr = 0; rr < 4; ++rr) acc2[rr][cj] = bv;
    }
    for (int k = 0; k < 256; k += 4) {
        float w2v[4][2];
#pragma unroll
        for (int kk = 0; kk < 4; ++kk)
#pragma unroll
            for (int cj = 0; cj < 2; ++cj) w2v[kk][cj] = W2[(k + kk) * N2 + c2 + 32 * cj];
#pragma unroll
        for (int rr = 0; rr < 4; ++rr) {
            float4 x = *(const float4*)&buf[4 * g2 + rr][k];
#pragma unroll
            for (int cj = 0; cj < 2; ++cj) {
                acc2[rr][cj] = fmaf(x.x, w2v[0][cj], acc2[rr][cj]);
                acc2[rr][cj] = fmaf(x.y, w2v[1][cj], acc2[rr][cj]);
                acc2[rr][cj] = fmaf(x.z, w2v[2][cj], acc2[rr][cj]);
                acc2[rr][cj] = fmaf(x.w, w2v[3][cj], acc2[rr][cj]);
            }
        }
    }
    const float w3a = W3[c2], w3b = W3[c2 + 32], b3v = b3[0];
    float p[4];
#pragma unroll
    for (int rr = 0; rr < 4; ++rr)
        p[rr] = fmaf(fmaxf(acc2[rr][0], 0.f), w3a, fmaxf(acc2[rr][1], 0.f) * w3b);
#pragma unroll
    for (int off = 16; off >= 1; off >>= 1)
#pragma unroll
        for (int rr = 0; rr < 4; ++rr) p[rr] += __shfl_xor(p[rr], off, 64);
    if (c2 == 0)
#pragma unroll
        for (int rr = 0; rr < 4; ++rr)
            out[r0 + 4 * g2 + rr] = 1.0f / (1.0f + __expf(-(p[rr] + b3v)));
}

extern "C" void kernel_launch(void* const* d_in, const int* in_sizes, int n_in,
                              void* d_out, int out_size, void* d_ws, size_t ws_size,
                              hipStream_t stream) {
    const float* nodes = (const float*)d_in[0];
    const float* newn  = (const float*)d_in[1];
    const float* W1    = (const float*)d_in[2];
    const float* b1    = (const float*)d_in[3];
    const float* W2    = (const float*)d_in[4];
    const float* b2    = (const float*)d_in[5];
    const float* W3    = (const float*)d_in[6];
    const float* b3    = (const float*)d_in[7];
    float* out = (float*)d_out;
    const int M = BB * SS;

    if (ws_size >= 163840) {               // 64K w1f + 32K w2f + 64K an
        __bf16* w1f = (__bf16*)d_ws;                   // 32768 elems
        __bf16* w2f = (__bf16*)d_ws + 32768;           // 16384 elems
        __bf16* anp = (__bf16*)d_ws + 49152;           // 32768 elems
        hipLaunchKernelGGL(prologue, dim3(24 + BB), dim3(256), 0, stream,
                           W1, W2, b1, newn, w1f, w2f, anp);
        hipLaunchKernelGGL(edge_mlp_mfma7, dim3(M / BROWS), dim3(512), 0, stream,
                           nodes, b2, W3, b3, w1f, w2f, anp, out);
    } else {
        hipLaunchKernelGGL(edge_mlp_f32, dim3(M / 32), dim3(256), 0, stream,
                           nodes, newn, W1, b1, W2, b2, W3, b3, out);
    }
}